// Round 7
// baseline (1932.220 us; speedup 1.0000x reference)
//
#include <hip/hip_runtime.h>
#include <hip/hip_bf16.h>
#include <stdint.h>

#define NN 100000
#define NE 1600000
#define NB 391     // ceil(NN/256)

typedef __attribute__((ext_vector_type(4))) float f32x4;
typedef __attribute__((ext_vector_type(2))) float f32x2;
typedef __attribute__((ext_vector_type(8))) __bf16 bf16x8;
typedef __attribute__((ext_vector_type(8))) short s16x8;
typedef __attribute__((ext_vector_type(4))) unsigned int u32x4;
typedef __attribute__((ext_vector_type(2))) unsigned int u32x2;

__device__ __forceinline__ unsigned short f2bf(float f) {
  unsigned int u = __builtin_bit_cast(unsigned int, f);
  u += 0x7fffu + ((u >> 16) & 1u);
  return (unsigned short)(u >> 16);
}

__device__ __forceinline__ f32x4 mfma16(bf16x8 a, bf16x8 b, f32x4 c) {
  return __builtin_amdgcn_mfma_f32_16x16x32_bf16(a, b, c, 0, 0, 0);
}

// ---------------------------------------------------------------------------
// setup: msg weights + global -> bf16
// ---------------------------------------------------------------------------
__global__ void convert_kernel(const float* __restrict__ w1, const float* __restrict__ w2,
                               const float* __restrict__ g,
                               unsigned short* __restrict__ w1b, unsigned short* __restrict__ w2b,
                               unsigned short* __restrict__ gb)
{
  const int tid = blockIdx.x * 256 + threadIdx.x;
  if (tid < 256 * 128) w1b[tid] = f2bf(w1[tid]);
  if (tid < 128 * 128) w2b[tid] = f2bf(w2[tid]);
  if (tid < 64) gb[tid] = f2bf(g[tid]);
}

// ---------------------------------------------------------------------------
// dual histogram (src and dst) in one pass
// ---------------------------------------------------------------------------
__global__ void hist2_kernel(const int* __restrict__ ei,
                             int* __restrict__ cnt_s, int* __restrict__ cnt_d)
{
  int i = blockIdx.x * 256 + threadIdx.x;
  const int stride = gridDim.x * 256;
  for (; i < NE; i += stride) {
    atomicAdd(&cnt_s[ei[i]], 1);
    atomicAdd(&cnt_d[ei[NE + i]], 1);
  }
}

// ---------------------------------------------------------------------------
// coalesced 3-kernel exclusive scan (parameterized; run once per sort key)
// ---------------------------------------------------------------------------
__global__ void scanA_kernel(const int* __restrict__ cnt, int* __restrict__ bsum)
{
  __shared__ int s[256];
  const int t = threadIdx.x;
  const int idx = blockIdx.x * 256 + t;
  s[t] = idx < NN ? cnt[idx] : 0;
  __syncthreads();
  for (int off = 128; off > 0; off >>= 1) {
    if (t < off) s[t] += s[t + off];
    __syncthreads();
  }
  if (t == 0) bsum[blockIdx.x] = s[0];
}

__global__ __launch_bounds__(512) void scanB_kernel(const int* __restrict__ bsum,
                                                    int* __restrict__ boff)
{
  __shared__ int s[512];
  const int t = threadIdx.x;
  const int v = t < NB ? bsum[t] : 0;
  s[t] = v;
  __syncthreads();
  for (int off = 1; off < 512; off <<= 1) {
    const int x = t >= off ? s[t - off] : 0;
    __syncthreads();
    s[t] += x;
    __syncthreads();
  }
  if (t < NB) boff[t] = s[t] - v;  // exclusive
}

__global__ void scanC_kernel(const int* __restrict__ cnt, const int* __restrict__ boff,
                             int* __restrict__ row_start, int* __restrict__ cursor)
{
  __shared__ int s[256];
  const int t = threadIdx.x;
  const int idx = blockIdx.x * 256 + t;
  const int v = idx < NN ? cnt[idx] : 0;
  s[t] = v;
  __syncthreads();
  for (int off = 1; off < 256; off <<= 1) {
    const int x = t >= off ? s[t - off] : 0;
    __syncthreads();
    s[t] += x;
    __syncthreads();
  }
  const int ex = s[t] - v + boff[blockIdx.x];
  if (idx < NN) { row_start[idx] = ex; cursor[idx] = ex; }
}

// ---------------------------------------------------------------------------
// scatter2: assign src-slot and dst-slot per edge.
// src_perm/dpos_perm are 6.4 MB (L2/L3-resident -> scattered 4B writes cheap)
// ---------------------------------------------------------------------------
__global__ void scatter2_kernel(const int* __restrict__ ei,
                                int* __restrict__ scur, int* __restrict__ dcur,
                                int* __restrict__ spos_at_e,
                                int* __restrict__ src_perm, int* __restrict__ dpos_perm)
{
  int i = blockIdx.x * 256 + threadIdx.x;
  const int stride = gridDim.x * 256;
  for (; i < NE; i += stride) {
    const int s = ei[i];
    const int d = ei[NE + i];
    const int sp = atomicAdd(&scur[s], 1);
    const int dp = atomicAdd(&dcur[d], 1);
    spos_at_e[i] = sp;
    src_perm[sp] = s;
    dpos_perm[sp] = dp;
  }
}

// ---------------------------------------------------------------------------
// permute: sequential edge_state read -> bf16 -> random (full 128B line)
// write to src-sorted slot. Chunked by slot range [lo,hi).
// ---------------------------------------------------------------------------
__global__ void permute_kernel(const float* __restrict__ edge_state,
                               const int* __restrict__ spos_at_e,
                               unsigned short* __restrict__ edge_bf,
                               int lo, int hi)
{
  int e = blockIdx.x * 256 + threadIdx.x;
  const int stride = gridDim.x * 256;
  for (; e < NE; e += stride) {
    const int sp = spos_at_e[e];
    if (sp >= lo && sp < hi) {
      const f32x4* es = (const f32x4*)(edge_state + (size_t)e * 64);
      unsigned short* orow = edge_bf + (size_t)(sp - lo) * 64;
#pragma unroll
      for (int c = 0; c < 8; ++c) {
        const f32x4 x0 = es[2 * c], x1 = es[2 * c + 1];
        unsigned short buf[8];
#pragma unroll
        for (int i = 0; i < 4; ++i) { buf[i] = f2bf(x0[i]); buf[4 + i] = f2bf(x1[i]); }
        *(u32x4*)(orow + c * 8) = *(u32x4*)buf;
      }
    }
  }
}

// ---------------------------------------------------------------------------
// edge msg kernel over SRC-SORTED slots:
// edge_bf sequential; node gathers have ~16x run reuse (L2-resident);
// msg row written fp8 to dst-sorted slot dpos_perm[slot] (random 128B line).
// Register-prefetch double buffer: tile t+grid's data gathered during tile t.
// ---------------------------------------------------------------------------
__global__ __launch_bounds__(256, 3) void edge_msg_kernel(
    const unsigned short* __restrict__ edge_bf,   // chunk-local [chunkSlots][64]
    const float* __restrict__ node_state,
    const int* __restrict__ src_perm,             // global slot -> src id
    const int* __restrict__ dpos_perm,            // global slot -> dst slot
    const unsigned short* __restrict__ w1b,
    const unsigned short* __restrict__ w2b,
    const float* __restrict__ bias1g,
    const float* __restrict__ bias2g,
    const unsigned short* __restrict__ gb,
    unsigned int* __restrict__ msg,               // [NE][32] u32 (128 fp8/row)
    int lo, int chunkSlots)
{
  __shared__ unsigned short sX[64 * 256];  // 32 KB staging; front 16 KB reused for msg tile
  __shared__ unsigned short sH[64 * 128];  // 16 KB h1
  __shared__ int sPos[64];

  const int t = threadIdx.x;
  const int lane = t & 63;
  const int wv = t >> 6;
  const int l15 = lane & 15;
  const int lq = lane >> 4;

  // preload W1/W2 B-fragments (per-wave column slice)
  bf16x8 b1f[8][2], b2f[4][2];
  float bs1[2], bs2[2];
  for (int n = 0; n < 2; ++n) {
    const int col = wv * 32 + n * 16 + l15;
    bs1[n] = bias1g[col];
    bs2[n] = bias2g[col];
    for (int ks = 0; ks < 8; ++ks) {
      const int k0 = ks * 32 + lq * 8;
      s16x8 v;
#pragma unroll
      for (int j = 0; j < 8; ++j) v[j] = (short)w1b[(k0 + j) * 128 + col];
      b1f[ks][n] = __builtin_bit_cast(bf16x8, v);
    }
    for (int ks = 0; ks < 4; ++ks) {
      const int k0 = ks * 32 + lq * 8;
      s16x8 v;
#pragma unroll
      for (int j = 0; j < 8; ++j) v[j] = (short)w2b[(k0 + j) * 128 + col];
      b2f[ks][n] = __builtin_bit_cast(bf16x8, v);
    }
  }

  const int r = t >> 2;   // edge row within tile
  const int p = t & 3;    // quarter of the row
  const int rs = r & 7;   // swizzle key

  u32x4 gR0, gR1;
  {
    const u32x4* g = (const u32x4*)(gb + p * 16);
    gR0 = g[0]; gR1 = g[1];
  }

  const int grid = gridDim.x;
  const int nT = chunkSlots / 64;

  // ---- prologue ----
  f32x4 pfN[8];
  u32x4 pfE[2];
  int srcNext, posNext, posCur;
  {
    const int le0 = min(blockIdx.x * 64 + r, chunkSlots - 1);
    const int s0 = src_perm[lo + le0];
    posCur = dpos_perm[lo + le0];
    const f32x4* nb = (const f32x4*)(node_state + (size_t)s0 * 128 + p * 32);
    const u32x4* eb = (const u32x4*)(edge_bf + (size_t)le0 * 64 + p * 16);
#pragma unroll
    for (int j = 0; j < 8; ++j) pfN[j] = nb[j];
    pfE[0] = eb[0]; pfE[1] = eb[1];
    const int le1 = min((blockIdx.x + grid) * 64 + r, chunkSlots - 1);
    srcNext = src_perm[lo + le1];
    posNext = dpos_perm[lo + le1];
  }

  for (int tl = blockIdx.x; tl < nT; tl += grid) {
    __syncthreads();  // prior iteration's out-store done reading sX front

    // ---- stage: reg -> LDS ----
    if (p == 0) sPos[r] = posCur;
#pragma unroll
    for (int j = 0; j < 4; ++j) {   // node chunks 0..15 (f32 -> bf16)
      unsigned short buf[8];
#pragma unroll
      for (int i = 0; i < 4; ++i) { buf[i] = f2bf(pfN[2 * j][i]); buf[4 + i] = f2bf(pfN[2 * j + 1][i]); }
      const int c = p * 4 + j;
      *(u32x4*)((char*)sX + r * 512 + ((c ^ rs) * 16)) = *(u32x4*)buf;
    }
    {  // edge chunks 16..23 (already bf16)
      const int c = 16 + 2 * p;
      *(u32x4*)((char*)sX + r * 512 + ((c ^ rs) * 16)) = pfE[0];
      *(u32x4*)((char*)sX + r * 512 + (((c + 1) ^ rs) * 16)) = pfE[1];
    }
    {  // global chunks 24..31
      const int c = 24 + 2 * p;
      *(u32x4*)((char*)sX + r * 512 + ((c ^ rs) * 16)) = gR0;
      *(u32x4*)((char*)sX + r * 512 + (((c + 1) ^ rs) * 16)) = gR1;
    }
    __syncthreads();

    // ---- issue next tile's gathers (latency hidden by MFMA) ----
    {
      const int tn = tl + grid;
      const int leN = min(tn * 64 + r, chunkSlots - 1);
      const f32x4* nb = (const f32x4*)(node_state + (size_t)srcNext * 128 + p * 32);
      const u32x4* eb = (const u32x4*)(edge_bf + (size_t)leN * 64 + p * 16);
#pragma unroll
      for (int j = 0; j < 8; ++j) pfN[j] = nb[j];
      pfE[0] = eb[0]; pfE[1] = eb[1];
      posCur = posNext;
      const int le2 = min((tn + grid) * 64 + r, chunkSlots - 1);
      srcNext = src_perm[lo + le2];
      posNext = dpos_perm[lo + le2];
    }

    // ---- phase 1: h1 = relu(X @ W1 + b1) ----
    f32x4 acc[4][2];
#pragma unroll
    for (int m = 0; m < 4; ++m)
#pragma unroll
      for (int n = 0; n < 2; ++n)
        acc[m][n] = (f32x4){bs1[n], bs1[n], bs1[n], bs1[n]};
#pragma unroll
    for (int ks = 0; ks < 8; ++ks) {
      bf16x8 a[4];
#pragma unroll
      for (int m = 0; m < 4; ++m) {
        const int row = m * 16 + l15;
        a[m] = *(const bf16x8*)((const char*)sX + row * 512 + (((4 * ks + lq) ^ (row & 7)) * 16));
      }
#pragma unroll
      for (int m = 0; m < 4; ++m)
#pragma unroll
        for (int n = 0; n < 2; ++n)
          acc[m][n] = mfma16(a[m], b1f[ks][n], acc[m][n]);
    }
#pragma unroll
    for (int m = 0; m < 4; ++m)
#pragma unroll
      for (int n = 0; n < 2; ++n)
#pragma unroll
        for (int i = 0; i < 4; ++i) {
          const int row = m * 16 + lq * 4 + i;
          const int col = wv * 32 + n * 16 + l15;
          float v = acc[m][n][i];
          v = v > 0.f ? v : 0.f;
          *(unsigned short*)((char*)sH + row * 256 +
                             ((((col >> 3) ^ (row & 7)) * 16) + (col & 7) * 2)) = f2bf(v);
        }
    __syncthreads();

    // ---- phase 2: msg = h1 @ W2 + b2 -> bf16 tile in sX front ----
    f32x4 acc2[4][2];
#pragma unroll
    for (int m = 0; m < 4; ++m)
#pragma unroll
      for (int n = 0; n < 2; ++n)
        acc2[m][n] = (f32x4){bs2[n], bs2[n], bs2[n], bs2[n]};
#pragma unroll
    for (int ks = 0; ks < 4; ++ks) {
      bf16x8 a[4];
#pragma unroll
      for (int m = 0; m < 4; ++m) {
        const int row = m * 16 + l15;
        a[m] = *(const bf16x8*)((const char*)sH + row * 256 + (((4 * ks + lq) ^ (row & 7)) * 16));
      }
#pragma unroll
      for (int m = 0; m < 4; ++m)
#pragma unroll
        for (int n = 0; n < 2; ++n)
          acc2[m][n] = mfma16(a[m], b2f[ks][n], acc2[m][n]);
    }
#pragma unroll
    for (int m = 0; m < 4; ++m)
#pragma unroll
      for (int n = 0; n < 2; ++n)
#pragma unroll
        for (int i = 0; i < 4; ++i) {
          const int row = m * 16 + lq * 4 + i;
          const int col = wv * 32 + n * 16 + l15;
          *(unsigned short*)((char*)sX + row * 256 +
                             ((((col >> 3) ^ (row & 7)) * 16) + (col & 7) * 2)) = f2bf(acc2[m][n][i]);
        }
    __syncthreads();

    // ---- out-store: row r quarter p -> fp8 at dst-sorted slot ----
    {
      const int pos = sPos[r];
      unsigned int* mrow = msg + (size_t)pos * 32;
#pragma unroll
      for (int cc = 4 * p; cc < 4 * p + 4; ++cc) {
        const u32x4 ch = *(const u32x4*)((const char*)sX + r * 256 + ((cc ^ rs) * 16));
        unsigned int w0 = 0, w1 = 0;
        float f[8];
#pragma unroll
        for (int q = 0; q < 4; ++q) {
          f[2 * q]     = __builtin_bit_cast(float, ch[q] << 16);
          f[2 * q + 1] = __builtin_bit_cast(float, ch[q] & 0xffff0000u);
        }
        w0 = __builtin_amdgcn_cvt_pk_fp8_f32(f[0], f[1], 0, false);
        w0 = __builtin_amdgcn_cvt_pk_fp8_f32(f[2], f[3], w0, true);
        w1 = __builtin_amdgcn_cvt_pk_fp8_f32(f[4], f[5], 0, false);
        w1 = __builtin_amdgcn_cvt_pk_fp8_f32(f[6], f[7], w1, true);
        *(u32x2*)(mrow + cc * 2) = (u32x2){(unsigned int)w0, (unsigned int)w1};
      }
    }
  }
}

// ---------------------------------------------------------------------------
// aggregate: sequential segmented sum over dst-sorted fp8 msg -> f32 agg
// ---------------------------------------------------------------------------
__global__ __launch_bounds__(256) void agg_kernel(
    const unsigned int* __restrict__ msg,
    const int* __restrict__ row_start,
    const int* __restrict__ cnt,
    float* __restrict__ agg)
{
  const int t = threadIdx.x;
  const int wv = t >> 6;
  const int lane = t & 63;
  const int half = lane >> 5;
  const int l32 = lane & 31;
  const int base = blockIdx.x * 64 + wv * 16;

  for (int k = 0; k < 8; ++k) {
    const int n = base + 2 * k + half;
    const bool act = n < NN;
    const int s = act ? row_start[n] : 0;
    const int c = act ? cnt[n] : 0;
    f32x4 acc = (f32x4){0.f, 0.f, 0.f, 0.f};
    for (int j = 0; j < c; ++j) {
      const int w = (int)msg[(size_t)(s + j) * 32 + l32];
      const f32x2 lo = __builtin_amdgcn_cvt_pk_f32_fp8(w, false);
      const f32x2 hi = __builtin_amdgcn_cvt_pk_f32_fp8(w, true);
      acc[0] += lo[0]; acc[1] += lo[1]; acc[2] += hi[0]; acc[3] += hi[1];
    }
    if (act) *(f32x4*)(agg + (size_t)n * 128 + l32 * 4) = acc;
  }
}

// ---------------------------------------------------------------------------
// update MLP phase 1 in full f32 (VALU): h1 = relu(X @ U1 + b1), K = 320
// ---------------------------------------------------------------------------
__global__ __launch_bounds__(128, 3) void upd1_kernel(
    const float* __restrict__ node_state,
    const float* __restrict__ agg,
    const int* __restrict__ cnt,
    const float* __restrict__ u1,    // [320][128] f32
    const float* __restrict__ b1,
    const float* __restrict__ gs,    // [64] f32
    float* __restrict__ h1out)
{
  const int n = blockIdx.x * 128 + threadIdx.x;
  const bool act = n < NN;
  const size_t row = (size_t)(act ? n : 0) * 128;

  f32x4 acc[32];
#pragma unroll
  for (int c = 0; c < 32; ++c) acc[c] = *(const f32x4*)(b1 + 4 * c);

  const float rdeg = act ? (1.0f / (float)max(cnt[n], 1)) : 0.0f;

  for (int k4 = 0; k4 < 32; ++k4) {
    const f32x4 x = *(const f32x4*)(node_state + row + 4 * k4);
#pragma unroll
    for (int kk = 0; kk < 4; ++kk) {
      const float xk = x[kk];
      const float* wr = u1 + (size_t)(4 * k4 + kk) * 128;
#pragma unroll
      for (int c = 0; c < 32; ++c) acc[c] += xk * *(const f32x4*)(wr + 4 * c);
    }
  }
  for (int k4 = 0; k4 < 32; ++k4) {
    const f32x4 x = *(const f32x4*)(agg + row + 4 * k4);
#pragma unroll
    for (int kk = 0; kk < 4; ++kk) {
      const float xk = x[kk] * rdeg;
      const float* wr = u1 + (size_t)(128 + 4 * k4 + kk) * 128;
#pragma unroll
      for (int c = 0; c < 32; ++c) acc[c] += xk * *(const f32x4*)(wr + 4 * c);
    }
  }
  for (int k = 0; k < 64; ++k) {
    const float xk = gs[k];
    const float* wr = u1 + (size_t)(256 + k) * 128;
#pragma unroll
    for (int c = 0; c < 32; ++c) acc[c] += xk * *(const f32x4*)(wr + 4 * c);
  }

  if (act) {
    float* o = h1out + (size_t)n * 128;
#pragma unroll
    for (int c = 0; c < 32; ++c) {
      f32x4 v = acc[c];
#pragma unroll
      for (int i = 0; i < 4; ++i) v[i] = v[i] > 0.f ? v[i] : 0.f;
      *(f32x4*)(o + 4 * c) = v;
    }
  }
}

// ---------------------------------------------------------------------------
// update MLP phase 2 + residual + LayerNorm, full f32 (VALU)
// ---------------------------------------------------------------------------
__global__ __launch_bounds__(128, 3) void upd2_kernel(
    const float* __restrict__ node_state,
    const float* __restrict__ h1,
    const float* __restrict__ u2,    // [128][128] f32
    const float* __restrict__ b2,
    const float* __restrict__ lng,
    const float* __restrict__ lnb,
    float* __restrict__ out)
{
  const int n = blockIdx.x * 128 + threadIdx.x;
  const bool act = n < NN;
  const size_t row = (size_t)(act ? n : 0) * 128;

  f32x4 acc[32];
#pragma unroll
  for (int c = 0; c < 32; ++c) acc[c] = *(const f32x4*)(b2 + 4 * c);

  for (int k4 = 0; k4 < 32; ++k4) {
    const f32x4 h = *(const f32x4*)(h1 + row + 4 * k4);
#pragma unroll
    for (int kk = 0; kk < 4; ++kk) {
      const float hk = h[kk];
      const float* wr = u2 + (size_t)(4 * k4 + kk) * 128;
#pragma unroll
      for (int c = 0; c < 32; ++c) acc[c] += hk * *(const f32x4*)(wr + 4 * c);
    }
  }

  if (act) {
    float s = 0.f, s2 = 0.f;
#pragma unroll
    for (int c = 0; c < 32; ++c) {
      const f32x4 nd = *(const f32x4*)(node_state + row + 4 * c);
      f32x4 x = nd + acc[c];
      acc[c] = x;
#pragma unroll
      for (int i = 0; i < 4; ++i) { s += x[i]; s2 += x[i] * x[i]; }
    }
    const float mu = s * (1.0f / 128.0f);
    float var = s2 * (1.0f / 128.0f) - mu * mu;
    var = var < 0.f ? 0.f : var;
    const float rstd = rsqrtf(var + 1e-5f);
    float* o = out + (size_t)n * 128;
#pragma unroll
    for (int c = 0; c < 32; ++c) {
      const f32x4 g = *(const f32x4*)(lng + 4 * c);
      const f32x4 b = *(const f32x4*)(lnb + 4 * c);
      f32x4 x = acc[c];
#pragma unroll
      for (int i = 0; i < 4; ++i) x[i] = (x[i] - mu) * rstd * g[i] + b[i];
      *(f32x4*)(o + 4 * c) = x;
    }
  }
}

// ---------------------------------------------------------------------------
extern "C" void kernel_launch(void* const* d_in, const int* in_sizes, int n_in,
                              void* d_out, int out_size, void* d_ws, size_t ws_size,
                              hipStream_t stream)
{
  const float* node_state = (const float*)d_in[0];
  const int* ei           = (const int*)d_in[1];   // int64 in reference -> int32 from harness
  const float* edge_state = (const float*)d_in[2];
  const float* gstate     = (const float*)d_in[3];
  const float* msg_w1     = (const float*)d_in[4];
  const float* msg_b1     = (const float*)d_in[5];
  const float* msg_w2     = (const float*)d_in[6];
  const float* msg_b2     = (const float*)d_in[7];
  const float* upd_w1     = (const float*)d_in[8];
  const float* upd_b1     = (const float*)d_in[9];
  const float* upd_w2     = (const float*)d_in[10];
  const float* upd_b2     = (const float*)d_in[11];
  const float* ln_g       = (const float*)d_in[12];
  const float* ln_b       = (const float*)d_in[13];

  char* ws = (char*)d_ws;
  float* agg       = (float*)(ws + 0);                  //  51,200,000
  int* cnt_d       = (int*)(ws + 51200000);             //     400,000
  int* cnt_s       = (int*)(ws + 51600000);             //     400,000
  int* row_d       = (int*)(ws + 52000000);             //     400,000
  int* dcur        = (int*)(ws + 52400000);             //     400,000
  int* scur        = (int*)(ws + 52800000);             //     400,000
  int* srow        = (int*)(ws + 53200000);             //     400,000 (unused output)
  int* bsum        = (int*)(ws + 53600000);             //       4,096
  int* boff        = (int*)(ws + 53604096);             //       4,096
  int* spos_at_e   = (int*)(ws + 53608192);             //   6,400,000
  int* src_perm    = (int*)(ws + 60008192);             //   6,400,000
  int* dpos_perm   = (int*)(ws + 66408192);             //   6,400,000
  unsigned short* w1b = (unsigned short*)(ws + 72808192);   // 65,536
  unsigned short* w2b = (unsigned short*)(ws + 72873728);   // 32,768
  unsigned short* gb  = (unsigned short*)(ws + 72906496);   // 128 (pad to 72,906,752)
  unsigned int* msgbuf = (unsigned int*)(ws + 72906752);    // 204,800,000 (fp8 [NE][128])
  float* h1buf        = (float*)(ws + 72906752);            // aliases msgbuf (msg dead by upd1)
  const size_t EBASE  = 277706752;                          // edge_bf region start
  (void)in_sizes; (void)n_in; (void)out_size;

  // flex edge_bf size to ws_size; last resort: use d_out (51.2 MB, dead until upd2)
  int nchunks;
  unsigned short* edge_bf;
  if (ws_size >= EBASE + 204800000ull)      { nchunks = 1; edge_bf = (unsigned short*)(ws + EBASE); }
  else if (ws_size >= EBASE + 102400000ull) { nchunks = 2; edge_bf = (unsigned short*)(ws + EBASE); }
  else if (ws_size >= EBASE + 51200000ull)  { nchunks = 4; edge_bf = (unsigned short*)(ws + EBASE); }
  else                                      { nchunks = 8; edge_bf = (unsigned short*)d_out; }
  const int chunkSlots = NE / nchunks;

  hipMemsetAsync(cnt_d, 0, 800000, stream);  // cnt_d + cnt_s (adjacent)
  hipLaunchKernelGGL(convert_kernel, dim3(128), dim3(256), 0, stream,
                     msg_w1, msg_w2, gstate, w1b, w2b, gb);
  hipLaunchKernelGGL(hist2_kernel, dim3(2048), dim3(256), 0, stream, ei, cnt_s, cnt_d);
  hipLaunchKernelGGL(scanA_kernel, dim3(NB), dim3(256), 0, stream, cnt_d, bsum);
  hipLaunchKernelGGL(scanB_kernel, dim3(1), dim3(512), 0, stream, bsum, boff);
  hipLaunchKernelGGL(scanC_kernel, dim3(NB), dim3(256), 0, stream, cnt_d, boff, row_d, dcur);
  hipLaunchKernelGGL(scanA_kernel, dim3(NB), dim3(256), 0, stream, cnt_s, bsum);
  hipLaunchKernelGGL(scanB_kernel, dim3(1), dim3(512), 0, stream, bsum, boff);
  hipLaunchKernelGGL(scanC_kernel, dim3(NB), dim3(256), 0, stream, cnt_s, boff, srow, scur);
  hipLaunchKernelGGL(scatter2_kernel, dim3(2048), dim3(256), 0, stream,
                     ei, scur, dcur, spos_at_e, src_perm, dpos_perm);
  for (int k = 0; k < nchunks; ++k) {
    const int lo = k * chunkSlots;
    hipLaunchKernelGGL(permute_kernel, dim3(2048), dim3(256), 0, stream,
                       edge_state, spos_at_e, edge_bf, lo, lo + chunkSlots);
    hipLaunchKernelGGL(edge_msg_kernel, dim3(768), dim3(256), 0, stream,
                       edge_bf, node_state, src_perm, dpos_perm,
                       w1b, w2b, msg_b1, msg_b2, gb, msgbuf, lo, chunkSlots);
  }
  hipLaunchKernelGGL(agg_kernel, dim3((NN + 63) / 64), dim3(256), 0, stream,
                     msgbuf, row_d, cnt_d, agg);
  hipLaunchKernelGGL(upd1_kernel, dim3((NN + 127) / 128), dim3(128), 0, stream,
                     node_state, agg, cnt_d, upd_w1, upd_b1, gstate, h1buf);
  hipLaunchKernelGGL(upd2_kernel, dim3((NN + 127) / 128), dim3(128), 0, stream,
                     node_state, h1buf, upd_w2, upd_b2, ln_g, ln_b, (float*)d_out);
}